// Round 8
// baseline (287.285 us; speedup 1.0000x reference)
//
#include <hip/hip_runtime.h>

#define N_NODES 50000
#define N_EDGES 600000
#define F 128
#define NRELL 9     // 8 relations + self-loop folded in as r=8
#define NB_SCAN 196 // ceil(50000/256)   (round-2 fallback path)
#define NB2 1563    // ceil(400000/256)  (v3 (dst,rel)-bin scan)

// ---------- v3 ws layout (all offsets 16-aligned) ----------
#define WT3_OFF   0                    // 294,912 B  bf16 W [r][o][i-swizzled]
#define H2_OFF    294912               // 12,800,000 B  bf16 h
#define GATE3_OFF 13094912             // 1,600,000 B  sigmoid gates [n][8]
#define CNT3_OFF  14694912             // 1,600,000 B  (dst,rel) histogram; reused as cursor
#define EXCL3_OFF 16294912             // 1,600,256 B  exclusive scan + sentinel
#define BSUM3_OFF 17895168             // 6,400 B  block sums for s1/s2/s3
#define REC3_OFF  17901568             // 4,800,000 B  packed {src, scale} per edge
#define WS_NEED3  ((size_t)22701568)   // A fused into LDS: no A buffer

// ---------- round-2 fallback ws layout ----------
#define GATE_OFF   294912
#define HREL_OFF   1894912
#define HREL_BYTES (9ll*N_NODES*128*2)
#define CNT_OFF    117094912
#define BASE_OFF   117294912
#define CUR_OFF    117494912
#define BSUM_OFF   117694912
#define SORT_OFF   117695936
#define WS_NEED2   ((size_t)120095936)
#define WS_NEED1   ((size_t)HREL_OFF + (size_t)HREL_BYTES)

// fused agg+GEMM geometry
#define FBN 32          // nodes per block
#define FGRID 1563      // ceil(50000/32), covers 50016 rows

typedef __attribute__((ext_vector_type(8))) short short8;
typedef __attribute__((ext_vector_type(4))) float floatx4;

__device__ inline unsigned short f32_to_bf16(float f) {
    unsigned u = __float_as_uint(f);
    unsigned r = u + 0x7fff + ((u >> 16) & 1);
    return (unsigned short)(r >> 16);
}
__device__ inline float bf16_to_f32(unsigned short s) {
    return __uint_as_float(((unsigned)s) << 16);
}
__device__ inline float bf16lo(unsigned m) { return __uint_as_float(m << 16); }
__device__ inline float bf16hi(unsigned m) { return __uint_as_float(m & 0xffff0000u); }
__device__ inline float sigmoidf(float x) { return 1.f / (1.f + __expf(-x)); }
__device__ inline unsigned packbf(float a0, float a1) {
    return (unsigned)f32_to_bf16(a0) | ((unsigned)f32_to_bf16(a1) << 16);
}

// ---------- v3: one-dispatch prep (W-pack | h-cast stream | gates | hist) ----------
// blockIdx ladder over four independent jobs (cnt pre-zeroed by memset):
//   [0, 576)        W + LW -> bf16 swizzled [r][o][i]
//   [576, 6826)     h -> bf16 pure stream (thread = 4 floats)
//   [6826, 7608)    gates: gw in registers, 16 nodes per wave
//   [7608, 9952)    (dst,rel) histogram atomics
__global__ __launch_bounds__(256) void k_prep(
    const float* __restrict__ h, const float* __restrict__ W,
    const float* __restrict__ gw, const float* __restrict__ lw,
    const int* __restrict__ dst, const int* __restrict__ rel,
    unsigned short* __restrict__ Wt, unsigned short* __restrict__ h2,
    float* __restrict__ gate, int* __restrict__ cnt)
{
    int vb = blockIdx.x, tid = threadIdx.x;
    if (vb < 576) {
        int idx = vb * 256 + tid;                 // exactly 147456
        int r = idx >> 14, rem = idx & 16383, i = rem >> 7, o = rem & 127;
        float v = (r < 8) ? W[(r << 14) + (i << 7) + o] : lw[(i << 7) + o];
        int g = (i >> 3) ^ (o & 7);               // 16B-granule XOR swizzle keyed on o
        Wt[(r << 14) + (o << 7) + (g << 3) + (i & 7)] = f32_to_bf16(v);
    } else if (vb < 6826) {
        int idx = (vb - 576) * 1024 + tid * 4;    // 6250*1024 = exactly 6.4M floats
        float4 v = *(const float4*)(h + idx);
        ushort4 b;
        b.x = f32_to_bf16(v.x); b.y = f32_to_bf16(v.y);
        b.z = f32_to_bf16(v.z); b.w = f32_to_bf16(v.w);
        *(ushort4*)(h2 + idx) = b;
    } else if (vb < 7608) {
        int wave = tid >> 6, lane = tid & 63;
        int wid = (vb - 6826) * 4 + wave;
        int n0 = wid * 16;                        // 782*4*16 = 50048 >= 50000
        int rl = lane >> 3, seg = lane & 7;
        const float4* wp = (const float4*)(gw + rl * F + seg * 16);
        float4 w0 = wp[0], w1 = wp[1], w2 = wp[2], w3 = wp[3];
        #pragma unroll 4
        for (int i = 0; i < 16; ++i) {
            int n = n0 + i;
            if (n >= N_NODES) break;
            const float4* hp = (const float4*)(h + (size_t)n * F + seg * 16);
            float4 a0 = hp[0], a1 = hp[1], a2 = hp[2], a3 = hp[3];
            float p = a0.x * w0.x + a0.y * w0.y + a0.z * w0.z + a0.w * w0.w;
            p += a1.x * w1.x + a1.y * w1.y + a1.z * w1.z + a1.w * w1.w;
            p += a2.x * w2.x + a2.y * w2.y + a2.z * w2.z + a2.w * w2.w;
            p += a3.x * w3.x + a3.y * w3.y + a3.z * w3.z + a3.w * w3.w;
            p += __shfl_xor(p, 1);
            p += __shfl_xor(p, 2);
            p += __shfl_xor(p, 4);
            if (seg == 0) gate[(size_t)n * 8 + rl] = sigmoidf(p);
        }
    } else {
        int e = (vb - 7608) * 256 + tid;
        if (e < N_EDGES) atomicAdd(&cnt[dst[e] * 8 + rel[e]], 1);
    }
}

// ---------- v3 3-phase scan over 400000 (dst,rel) bins ----------
__global__ void k_s1(const int* __restrict__ cnt, int* __restrict__ excl,
                     int* __restrict__ bsum) {
    __shared__ int sh[256];
    int g = blockIdx.x * 256 + threadIdx.x;
    int v = (g < 400000) ? cnt[g] : 0;
    sh[threadIdx.x] = v;
    __syncthreads();
    #pragma unroll
    for (int off = 1; off < 256; off <<= 1) {
        int t = (threadIdx.x >= off) ? sh[threadIdx.x - off] : 0;
        __syncthreads();
        sh[threadIdx.x] += t;
        __syncthreads();
    }
    if (g < 400000) excl[g] = sh[threadIdx.x] - v;
    if (threadIdx.x == 255) bsum[blockIdx.x] = sh[255];
}

__global__ void k_s2(int* __restrict__ bsum) {   // scan NB2=1563 block sums, 1 block
    __shared__ int sh[256];
    int t = threadIdx.x;
    int v[7];
    int s = 0;
    #pragma unroll
    for (int j = 0; j < 7; ++j) {
        int idx = t * 7 + j;
        v[j] = (idx < NB2) ? bsum[idx] : 0;
        s += v[j];
    }
    sh[t] = s;
    __syncthreads();
    #pragma unroll
    for (int off = 1; off < 256; off <<= 1) {
        int tt = (t >= off) ? sh[t - off] : 0;
        __syncthreads();
        sh[t] += tt;
        __syncthreads();
    }
    int run = sh[t] - s;
    #pragma unroll
    for (int j = 0; j < 7; ++j) {
        int idx = t * 7 + j;
        if (idx < NB2) bsum[idx] = run;
        run += v[j];
    }
}

__global__ void k_s3(int* __restrict__ excl, const int* __restrict__ bsum,
                     int* __restrict__ cursor) {
    int g = blockIdx.x * 256 + threadIdx.x;
    if (g < 400000) {
        int b = excl[g] + bsum[blockIdx.x];
        excl[g] = b;
        cursor[g] = b;
    }
    if (g == 0) excl[400000] = N_EDGES;   // sentinel
}

__global__ void k_scatter2(const int* __restrict__ src, const int* __restrict__ dst,
                           const int* __restrict__ rel, const float* __restrict__ norm,
                           const float* __restrict__ gate, int* __restrict__ cursor,
                           int2* __restrict__ rec) {
    int e = blockIdx.x * 256 + threadIdx.x;
    if (e >= N_EDGES) return;
    int d = dst[e], r = rel[e], s = src[e];
    int pos = atomicAdd(&cursor[d * 8 + r], 1);
    float sc = norm[e] * gate[(size_t)s * 8 + r];
    rec[pos] = make_int2(s, __float_as_int(sc));
}

// ---------- v3 fused: per-node aggregation into LDS + GEMM; A never hits HBM ----------
// Block = 32 nodes, 8 waves (512 thr). LDS sA[32][1152] = 73.7KB -> 2 blocks/CU
// (fixes round-2's 1-block/CU failure). Gather: each wave owns 4 nodes, aggA's
// proven inner loop, writes granule-swizzled LDS rows. GEMM: wave computes a
// 32x16 output tile; A via conflict-free ds_read_b128; B straight from L2-hot
// Wt (288KB resident, no LDS staging). Accumulation order identical to the
// previous aggA+gemmA pair -> bit-identical output.
__global__ __launch_bounds__(512, 4) void k_fused(
    const unsigned short* __restrict__ h2,
    const int2* __restrict__ rec,
    const int* __restrict__ excl,
    const unsigned short* __restrict__ Wt,
    const float* __restrict__ bias,
    float* __restrict__ out)
{
    __shared__ unsigned short sA[FBN * 1152];   // 73,728 B
    unsigned* sAu = (unsigned*)sA;
    int tid = threadIdx.x;
    int wave = tid >> 6, lane = tid & 63;
    int nb = blockIdx.x * FBN;

    // ---- gather: wave handles nodes nb+wave*4 .. +3 ----
    #pragma unroll
    for (int i = 0; i < 4; ++i) {
        int n = nb + wave * 4 + i;
        int lr = wave * 4 + i;                   // LDS row 0..31
        int bin = n * 8 + lane;
        int ex = 0;
        if (lane < 9) ex = excl[bin <= 400000 ? bin : 400000];  // pad nodes -> sentinel
        int e0 = __shfl(ex, 0), e8 = __shfl(ex, 8);
        int deg = e8 - e0;
        unsigned* aw = sAu + lr * 576 + (((lane >> 2) ^ (lr & 7)) << 2) + (lane & 3);

        if (deg <= 64) {
            int rs = 0; float rsc = 0.f;
            if (lane < deg) {
                int2 rc = rec[e0 + lane];
                rs = rc.x; rsc = __int_as_float(rc.y);
            }
            for (int r = 0; r < 8; ++r) {
                int s = __shfl(ex, r) - e0;
                int e = __shfl(ex, r + 1) - e0;
                float a0 = 0.f, a1 = 0.f;
                for (int j = s; j < e; ++j) {
                    int sj = __shfl(rs, j);
                    float sc = __shfl(rsc, j);
                    unsigned m = *(const unsigned*)(h2 + (size_t)sj * F + lane * 2);
                    a0 += sc * bf16lo(m);
                    a1 += sc * bf16hi(m);
                }
                aw[r * 64] = packbf(a0, a1);
            }
        } else {   // safety path for high-degree nodes
            for (int r = 0; r < 8; ++r) {
                int s = __shfl(ex, r);
                int e = __shfl(ex, r + 1);
                float a0 = 0.f, a1 = 0.f;
                for (int idx = s; idx < e; ++idx) {
                    int2 rc = rec[idx];                       // wave-uniform broadcast load
                    float sc = __int_as_float(rc.y);
                    unsigned m = *(const unsigned*)(h2 + (size_t)rc.x * F + lane * 2);
                    a0 += sc * bf16lo(m);
                    a1 += sc * bf16hi(m);
                }
                aw[r * 64] = packbf(a0, a1);
            }
        }
        // r=8 self-loop slice: copy h2 row (zeros for pad rows)
        unsigned hm = 0;
        if (n < N_NODES) hm = ((const unsigned*)(h2 + (size_t)n * F))[lane];
        aw[512] = hm;
    }
    __syncthreads();

    // ---- GEMM: wave -> 32 rows x 16 cols (col block wave*16) ----
    int lrow = lane & 15, quad = lane >> 4;
    int sk = lrow & 7;
    const unsigned short* Bcol = Wt + ((wave * 16 + lrow) << 7);  // o*128 shorts
    floatx4 acc0 = (floatx4){0.f, 0.f, 0.f, 0.f};
    floatx4 acc1 = (floatx4){0.f, 0.f, 0.f, 0.f};
    for (int r = 0; r < 9; ++r) {
        #pragma unroll
        for (int kt = 0; kt < 4; ++kt) {
            int gphys = ((kt * 4 + quad) ^ sk) << 3;
            short8 b  = *(const short8*)(Bcol + (r << 14) + gphys);
            short8 a0 = *(const short8*)(&sA[lrow * 1152 + r * 128 + gphys]);
            short8 a1 = *(const short8*)(&sA[(16 + lrow) * 1152 + r * 128 + gphys]);
            acc0 = __builtin_amdgcn_mfma_f32_16x16x32_bf16(a0, b, acc0, 0, 0, 0);
            acc1 = __builtin_amdgcn_mfma_f32_16x16x32_bf16(a1, b, acc1, 0, 0, 0);
        }
    }
    int col = wave * 16 + lrow;
    float bv = bias[col];
    #pragma unroll
    for (int g = 0; g < 4; ++g) {
        int row0 = nb + quad * 4 + g;
        if (row0 < N_NODES) out[(size_t)row0 * F + col] = fmaxf(acc0[g] + bv, 0.f);
        int row1 = nb + 16 + quad * 4 + g;
        if (row1 < N_NODES) out[(size_t)row1 * F + col] = fmaxf(acc1[g] + bv, 0.f);
    }
}

// ================= legacy fallback path kernels =================
__global__ void k_prep_w(const float* __restrict__ W, const float* __restrict__ LW,
                         unsigned short* __restrict__ Wt, int swz) {
    int idx = blockIdx.x * 256 + threadIdx.x;
    if (idx >= 9 * 128 * 128) return;
    int r = idx >> 14;
    int rem = idx & 16383;
    int i = rem >> 7, o = rem & 127;
    float v = (r < 8) ? W[(r << 14) + (i << 7) + o] : LW[(i << 7) + o];
    int pos;
    if (swz) {
        int g = (i >> 3) ^ (o & 7);
        pos = (r << 14) + (o << 7) + (g << 3) + (i & 7);
    } else {
        pos = (r << 14) + (o << 7) + i;
    }
    Wt[pos] = f32_to_bf16(v);
}

__global__ void k_gate(const float* __restrict__ h, const float* __restrict__ gw,
                       float* __restrict__ gate) {
    int wave = threadIdx.x >> 6, lane = threadIdx.x & 63;
    int n = blockIdx.x * 4 + wave;
    if (n >= N_NODES) return;
    float2 hv = *(const float2*)(h + (size_t)n * F + lane * 2);
    #pragma unroll
    for (int r = 0; r < 8; ++r) {
        float2 wv = *(const float2*)(gw + r * F + lane * 2);
        float p = hv.x * wv.x + hv.y * wv.y;
        #pragma unroll
        for (int off = 32; off; off >>= 1) p += __shfl_xor(p, off);
        if (lane == 0) gate[r * N_NODES + n] = sigmoidf(p);
    }
}

#define LDH 136
#define LDW 136
__global__ __launch_bounds__(256) void k_hrel(const float* __restrict__ h,
                                              const unsigned short* __restrict__ Wt,
                                              unsigned short* __restrict__ hrel) {
    __shared__ unsigned short hA[64 * LDH];
    __shared__ unsigned short wB[128 * LDW];
    int tid = threadIdx.x;
    int nb = blockIdx.x * 64;
    #pragma unroll
    for (int it = 0; it < 8; ++it) {
        int idx = it * 1024 + tid * 4;
        int row = idx >> 7, col = idx & 127;
        int node = nb + row;
        float4 v;
        if (node < N_NODES) v = *(const float4*)(h + (size_t)node * F + col);
        else                v = make_float4(0.f, 0.f, 0.f, 0.f);
        ushort4 b;
        b.x = f32_to_bf16(v.x); b.y = f32_to_bf16(v.y);
        b.z = f32_to_bf16(v.z); b.w = f32_to_bf16(v.w);
        *(ushort4*)(&hA[row * LDH + col]) = b;
    }
    int wave = tid >> 6, lane = tid & 63;
    int lrow = lane & 15, quad = lane >> 4;
    const unsigned short* aptr = &hA[(wave * 16 + lrow) * LDH + quad * 8];
    for (int r = 0; r < NRELL; ++r) {
        __syncthreads();
        #pragma unroll
        for (int it = 0; it < 8; ++it) {
            int idx = it * 2048 + tid * 8;
            int o = idx >> 7, i = idx & 127;
            *(uint4*)(&wB[o * LDW + i]) = *(const uint4*)(Wt + (r << 14) + idx);
        }
        __syncthreads();
        floatx4 acc[8];
        #pragma unroll
        for (int nt = 0; nt < 8; ++nt) acc[nt] = (floatx4){0.f, 0.f, 0.f, 0.f};
        #pragma unroll
        for (int kt = 0; kt < 4; ++kt) {
            short8 a = *(const short8*)(aptr + kt * 32);
            #pragma unroll
            for (int nt = 0; nt < 8; ++nt) {
                short8 b = *(const short8*)(&wB[(nt * 16 + lrow) * LDW + kt * 32 + quad * 8]);
                acc[nt] = __builtin_amdgcn_mfma_f32_16x16x32_bf16(a, b, acc[nt], 0, 0, 0);
            }
        }
        unsigned short* dstp = hrel + (size_t)r * N_NODES * F;
        #pragma unroll
        for (int nt = 0; nt < 8; ++nt) {
            #pragma unroll
            for (int g = 0; g < 4; ++g) {
                int node = nb + wave * 16 + quad * 4 + g;
                if (node < N_NODES)
                    dstp[(size_t)node * F + nt * 16 + lrow] = f32_to_bf16(acc[nt][g]);
            }
        }
    }
}

__global__ void k_hist(const int* __restrict__ dst, int* __restrict__ cnt) {
    int e = blockIdx.x * 256 + threadIdx.x;
    if (e < N_EDGES) atomicAdd(&cnt[dst[e]], 1);
}

__global__ void k_scan1(const int* __restrict__ cnt, int* __restrict__ excl,
                        int* __restrict__ bsum) {
    __shared__ int sh[256];
    int g = blockIdx.x * 256 + threadIdx.x;
    int v = (g < N_NODES) ? cnt[g] : 0;
    sh[threadIdx.x] = v;
    __syncthreads();
    #pragma unroll
    for (int off = 1; off < 256; off <<= 1) {
        int t = (threadIdx.x >= off) ? sh[threadIdx.x - off] : 0;
        __syncthreads();
        sh[threadIdx.x] += t;
        __syncthreads();
    }
    if (g < N_NODES) excl[g] = sh[threadIdx.x] - v;
    if (threadIdx.x == 255) bsum[blockIdx.x] = sh[255];
}

__global__ void k_scan2(int* __restrict__ bsum) {
    __shared__ int sh[256];
    int v = (threadIdx.x < NB_SCAN) ? bsum[threadIdx.x] : 0;
    sh[threadIdx.x] = v;
    __syncthreads();
    #pragma unroll
    for (int off = 1; off < 256; off <<= 1) {
        int t = (threadIdx.x >= off) ? sh[threadIdx.x - off] : 0;
        __syncthreads();
        sh[threadIdx.x] += t;
        __syncthreads();
    }
    if (threadIdx.x < NB_SCAN) bsum[threadIdx.x] = sh[threadIdx.x] - v;
}

__global__ void k_scan3(int* __restrict__ excl, const int* __restrict__ bsum,
                        int* __restrict__ cursor) {
    int g = blockIdx.x * 256 + threadIdx.x;
    if (g < N_NODES) {
        int b = excl[g] + bsum[blockIdx.x];
        excl[g] = b;
        cursor[g] = b;
    }
}

__global__ void k_scatter(const int* __restrict__ dst, int* __restrict__ cursor,
                          int* __restrict__ sorted) {
    int e = blockIdx.x * 256 + threadIdx.x;
    if (e < N_EDGES) {
        int pos = atomicAdd(&cursor[dst[e]], 1);
        sorted[pos] = e;
    }
}

__global__ __launch_bounds__(256) void k_agg(const unsigned short* __restrict__ hrel,
                      const float* __restrict__ gate,
                      const float* __restrict__ norm,
                      const int* __restrict__ src, const int* __restrict__ rel,
                      const int* __restrict__ sorted,
                      const int* __restrict__ base, const int* __restrict__ cnt,
                      const float* __restrict__ bias,
                      float* __restrict__ out) {
    int wave = threadIdx.x >> 6, lane = threadIdx.x & 63;
    int n = blockIdx.x * 4 + wave;
    if (n >= N_NODES) return;
    int startp = base[n];
    int deg = cnt[n];
    float acc0 = 0.f, acc1 = 0.f;
    for (int c0 = 0; c0 < deg; c0 += 64) {
        int myi = c0 + lane;
        float sc = 0.f;
        int row = 0;
        if (myi < deg) {
            int e = sorted[startp + myi];
            int s = src[e], r = rel[e];
            row = r * N_NODES + s;
            sc = norm[e] * gate[row];
        }
        int lim = (deg - c0 < 64) ? (deg - c0) : 64;
        for (int i = 0; i < lim; ++i) {
            float scl = __shfl(sc, i);
            int rw = __shfl(row, i);
            unsigned m = *(const unsigned*)(hrel + (size_t)rw * F + lane * 2);
            acc0 += scl * bf16lo(m);
            acc1 += scl * bf16hi(m);
        }
    }
    const unsigned short* hrel8 = hrel + (size_t)8 * N_NODES * F;
    unsigned l8 = *(const unsigned*)(hrel8 + (size_t)n * F + lane * 2);
    float2 bv = *(const float2*)(bias + lane * 2);
    float o0 = fmaxf(acc0 + bv.x + bf16lo(l8), 0.f);
    float o1 = fmaxf(acc1 + bv.y + bf16hi(l8), 0.f);
    *(float2*)(out + (size_t)n * F + lane * 2) = make_float2(o0, o1);
}

__global__ void k_edges(const unsigned short* __restrict__ hrel,
                        const float* __restrict__ gate,
                        const float* __restrict__ norm,
                        const int* __restrict__ src, const int* __restrict__ dst,
                        const int* __restrict__ rel,
                        float* __restrict__ out) {
    int wave = threadIdx.x >> 6, lane = threadIdx.x & 63;
    int e = blockIdx.x * 4 + wave;
    if (e >= N_EDGES) return;
    int s = src[e], d = dst[e], r = rel[e];
    float scale = norm[e] * gate[r * N_NODES + s];
    unsigned int m = *(const unsigned int*)(hrel + ((size_t)r * N_NODES + s) * F + lane * 2);
    float v0 = bf16lo(m) * scale;
    float v1 = bf16hi(m) * scale;
    float* op = out + (size_t)d * F + lane * 2;
    unsafeAtomicAdd(op, v0);
    unsafeAtomicAdd(op + 1, v1);
}

__global__ void k_final(float* __restrict__ out, const float* __restrict__ bias,
                        const unsigned short* __restrict__ hrel8) {
    int idx = blockIdx.x * 256 + threadIdx.x;
    if (idx >= N_NODES * 32) return;
    int node = idx >> 5, c4 = (idx & 31) * 4;
    float4 a = *(float4*)(out + (size_t)node * F + c4);
    float4 b = *(const float4*)(bias + c4);
    ushort4 l = *(const ushort4*)(hrel8 + (size_t)node * F + c4);
    float o0 = fmaxf(a.x + b.x + bf16_to_f32(l.x), 0.f);
    float o1 = fmaxf(a.y + b.y + bf16_to_f32(l.y), 0.f);
    float o2 = fmaxf(a.z + b.z + bf16_to_f32(l.z), 0.f);
    float o3 = fmaxf(a.w + b.w + bf16_to_f32(l.w), 0.f);
    *(float4*)(out + (size_t)node * F + c4) = make_float4(o0, o1, o2, o3);
}

__global__ void k_edges_fb(const float* __restrict__ h, const float* __restrict__ W,
                           const float* __restrict__ gw, const float* __restrict__ norm,
                           const int* __restrict__ src, const int* __restrict__ dst,
                           const int* __restrict__ rel, float* __restrict__ out) {
    int wave = threadIdx.x >> 6, lane = threadIdx.x & 63;
    int e = blockIdx.x * 4 + wave;
    if (e >= N_EDGES) return;
    int s = src[e], d = dst[e], r = rel[e];
    float2 hv = *(const float2*)(h + (size_t)s * F + lane * 2);
    float2 gv = *(const float2*)(gw + r * F + lane * 2);
    float p = hv.x * gv.x + hv.y * gv.y;
    #pragma unroll
    for (int off = 32; off; off >>= 1) p += __shfl_xor(p, off);
    float scale = norm[e] * sigmoidf(p);
    const float* wr = W + ((size_t)r << 14);
    float a0 = 0.f, a1 = 0.f;
    for (int i2 = 0; i2 < 64; ++i2) {
        float x0 = __shfl(hv.x, i2), x1 = __shfl(hv.y, i2);
        a0 += x0 * wr[(2 * i2) * F + lane]      + x1 * wr[(2 * i2 + 1) * F + lane];
        a1 += x0 * wr[(2 * i2) * F + 64 + lane] + x1 * wr[(2 * i2 + 1) * F + 64 + lane];
    }
    unsafeAtomicAdd(out + (size_t)d * F + lane,      a0 * scale);
    unsafeAtomicAdd(out + (size_t)d * F + 64 + lane, a1 * scale);
}

__global__ void k_final_fb(const float* __restrict__ h, const float* __restrict__ LW,
                           const float* __restrict__ bias, float* __restrict__ out) {
    int wave = threadIdx.x >> 6, lane = threadIdx.x & 63;
    int n = blockIdx.x * 4 + wave;
    if (n >= N_NODES) return;
    float2 hv = *(const float2*)(h + (size_t)n * F + lane * 2);
    float a0 = 0.f, a1 = 0.f;
    for (int i2 = 0; i2 < 64; ++i2) {
        float x0 = __shfl(hv.x, i2), x1 = __shfl(hv.y, i2);
        a0 += x0 * LW[(2 * i2) * F + lane]      + x1 * LW[(2 * i2 + 1) * F + lane];
        a1 += x0 * LW[(2 * i2) * F + 64 + lane] + x1 * LW[(2 * i2 + 1) * F + 64 + lane];
    }
    float* op = out + (size_t)n * F;
    op[lane]      = fmaxf(op[lane]      + bias[lane]      + a0, 0.f);
    op[64 + lane] = fmaxf(op[64 + lane] + bias[64 + lane] + a1, 0.f);
}

extern "C" void kernel_launch(void* const* d_in, const int* in_sizes, int n_in,
                              void* d_out, int out_size, void* d_ws, size_t ws_size,
                              hipStream_t stream) {
    const float* h    = (const float*)d_in[0];
    const float* W    = (const float*)d_in[1];
    const float* gw   = (const float*)d_in[2];
    const float* bias = (const float*)d_in[3];
    const float* lw   = (const float*)d_in[4];
    const float* norm = (const float*)d_in[5];
    const int* src    = (const int*)d_in[6];
    const int* dst    = (const int*)d_in[7];
    const int* rel    = (const int*)d_in[8];
    float* out = (float*)d_out;

    if (ws_size >= WS_NEED3) {
        unsigned short* Wt   = (unsigned short*)((char*)d_ws + WT3_OFF);
        unsigned short* h2   = (unsigned short*)((char*)d_ws + H2_OFF);
        float*          gate = (float*)((char*)d_ws + GATE3_OFF);
        int*            cnt  = (int*)((char*)d_ws + CNT3_OFF);   // reused as cursor
        int*            excl = (int*)((char*)d_ws + EXCL3_OFF);
        int*            bsum = (int*)((char*)d_ws + BSUM3_OFF);
        int2*           rec  = (int2*)((char*)d_ws + REC3_OFF);

        hipMemsetAsync(cnt, 0, 400000 * sizeof(int), stream);
        k_prep<<<9952, 256, 0, stream>>>(h, W, gw, lw, dst, rel, Wt, h2, gate, cnt);
        k_s1<<<NB2, 256, 0, stream>>>(cnt, excl, bsum);
        k_s2<<<1, 256, 0, stream>>>(bsum);
        k_s3<<<NB2, 256, 0, stream>>>(excl, bsum, cnt);
        k_scatter2<<<2344, 256, 0, stream>>>(src, dst, rel, norm, gate, cnt, rec);
        k_fused<<<FGRID, 512, 0, stream>>>(h2, rec, excl, Wt, bias, out);
    } else if (ws_size >= WS_NEED2) {
        unsigned short* Wt   = (unsigned short*)d_ws;
        float*          gate = (float*)((char*)d_ws + GATE_OFF);
        unsigned short* hrel = (unsigned short*)((char*)d_ws + HREL_OFF);
        int* cnt    = (int*)((char*)d_ws + CNT_OFF);
        int* base   = (int*)((char*)d_ws + BASE_OFF);
        int* cursor = (int*)((char*)d_ws + CUR_OFF);
        int* bsum   = (int*)((char*)d_ws + BSUM_OFF);
        int* sorted = (int*)((char*)d_ws + SORT_OFF);
        hipMemsetAsync(cnt, 0, N_NODES * sizeof(int), stream);
        k_prep_w<<<576, 256, 0, stream>>>(W, lw, Wt, 0);
        k_gate<<<12500, 256, 0, stream>>>(h, gw, gate);
        k_hist<<<2344, 256, 0, stream>>>(dst, cnt);
        k_scan1<<<NB_SCAN, 256, 0, stream>>>(cnt, base, bsum);
        k_scan2<<<1, 256, 0, stream>>>(bsum);
        k_scan3<<<NB_SCAN, 256, 0, stream>>>(base, bsum, cursor);
        k_scatter<<<2344, 256, 0, stream>>>(dst, cursor, sorted);
        k_hrel<<<782, 256, 0, stream>>>(h, Wt, hrel);
        k_agg<<<12500, 256, 0, stream>>>(hrel, gate, norm, src, rel, sorted,
                                         base, cnt, bias, out);
    } else if (ws_size >= WS_NEED1) {
        unsigned short* Wt   = (unsigned short*)d_ws;
        float*          gate = (float*)((char*)d_ws + GATE_OFF);
        unsigned short* hrel = (unsigned short*)((char*)d_ws + HREL_OFF);
        hipMemsetAsync(d_out, 0, (size_t)out_size * sizeof(float), stream);
        k_prep_w<<<576, 256, 0, stream>>>(W, lw, Wt, 0);
        k_gate<<<12500, 256, 0, stream>>>(h, gw, gate);
        k_hrel<<<782, 256, 0, stream>>>(h, Wt, hrel);
        k_edges<<<150000, 256, 0, stream>>>(hrel, gate, norm, src, dst, rel, out);
        k_final<<<6250, 256, 0, stream>>>(out, bias, hrel + (size_t)8 * N_NODES * F);
    } else {
        hipMemsetAsync(d_out, 0, (size_t)out_size * sizeof(float), stream);
        k_edges_fb<<<150000, 256, 0, stream>>>(h, W, gw, norm, src, dst, rel, out);
        k_final_fb<<<12500, 256, 0, stream>>>(h, lw, bias, out);
    }
}

// Round 9
// 257.652 us; speedup vs baseline: 1.1150x; 1.1150x over previous
//
#include <hip/hip_runtime.h>

#define N_NODES 50000
#define N_EDGES 600000
#define F 128
#define NRELL 9     // 8 relations + self-loop folded in as r=8
#define NB_SCAN 196 // ceil(50000/256)   (round-2 fallback path)
#define NB2 1563    // ceil(400000/256)  (v3 (dst,rel)-bin scan)

// ---------- v3 ws layout (all offsets 16-aligned) ----------
#define WT3_OFF   0                    // 294,912 B  bf16 W [r][o][i-swizzled]
#define H2_OFF    294912               // 12,800,000 B  bf16 h
#define GATE3_OFF 13094912             // 1,600,000 B  sigmoid gates [n][8]
#define CNT3_OFF  14694912             // 1,600,000 B  (dst,rel) histogram; reused as cursor
#define EXCL3_OFF 16294912             // 1,600,256 B  per-block-local exclusive scan
#define BSUM3_OFF 17895168             // 6,400 B  block sums (exclusive after s2)
#define REC3_OFF  17901568             // 4,800,000 B  packed {src, scale} per edge
#define A3_OFF    22701568             // 102,498,304 B  bf16 A [n][8][128] (swizzled), 50048 rows
#define WS_NEED3  ((size_t)125199872)

// ---------- round-2 fallback ws layout ----------
#define GATE_OFF   294912
#define HREL_OFF   1894912
#define HREL_BYTES (9ll*N_NODES*128*2)
#define CNT_OFF    117094912
#define BASE_OFF   117294912
#define CUR_OFF    117494912
#define BSUM_OFF   117694912
#define SORT_OFF   117695936
#define WS_NEED2   ((size_t)120095936)
#define WS_NEED1   ((size_t)HREL_OFF + (size_t)HREL_BYTES)

typedef __attribute__((ext_vector_type(8))) short short8;
typedef __attribute__((ext_vector_type(4))) float floatx4;

__device__ inline unsigned short f32_to_bf16(float f) {
    unsigned u = __float_as_uint(f);
    unsigned r = u + 0x7fff + ((u >> 16) & 1);
    return (unsigned short)(r >> 16);
}
__device__ inline float bf16_to_f32(unsigned short s) {
    return __uint_as_float(((unsigned)s) << 16);
}
__device__ inline float bf16lo(unsigned m) { return __uint_as_float(m << 16); }
__device__ inline float bf16hi(unsigned m) { return __uint_as_float(m & 0xffff0000u); }
__device__ inline float sigmoidf(float x) { return 1.f / (1.f + __expf(-x)); }
__device__ inline unsigned packbf(float a0, float a1) {
    return (unsigned)f32_to_bf16(a0) | ((unsigned)f32_to_bf16(a1) << 16);
}

// async global->LDS, 16B per lane; lds dst is wave-uniform base (+lane*16 by HW),
// global src is per-lane
__device__ __forceinline__ void gload_lds16(const void* gsrc, void* ldst) {
    __builtin_amdgcn_global_load_lds(
        (const __attribute__((address_space(1))) void*)gsrc,
        (__attribute__((address_space(3))) void*)ldst, 16, 0, 0);
}

// ---------- v3: one-dispatch prep (W-pack | h-cast stream | gates | hist) ----------
// blockIdx ladder over four independent jobs (cnt pre-zeroed by memset):
//   [0, 576)        W + LW -> bf16 swizzled [r][o][i]
//   [576, 6826)     h -> bf16 pure stream (thread = 4 floats)
//   [6826, 7608)    gates: gw in registers, 16 nodes per wave
//   [7608, 9952)    (dst,rel) histogram atomics
__global__ __launch_bounds__(256) void k_prep(
    const float* __restrict__ h, const float* __restrict__ W,
    const float* __restrict__ gw, const float* __restrict__ lw,
    const int* __restrict__ dst, const int* __restrict__ rel,
    unsigned short* __restrict__ Wt, unsigned short* __restrict__ h2,
    float* __restrict__ gate, int* __restrict__ cnt)
{
    int vb = blockIdx.x, tid = threadIdx.x;
    if (vb < 576) {
        int idx = vb * 256 + tid;                 // exactly 147456
        int r = idx >> 14, rem = idx & 16383, i = rem >> 7, o = rem & 127;
        float v = (r < 8) ? W[(r << 14) + (i << 7) + o] : lw[(i << 7) + o];
        int g = (i >> 3) ^ (o & 7);               // 16B-granule XOR swizzle keyed on o
        Wt[(r << 14) + (o << 7) + (g << 3) + (i & 7)] = f32_to_bf16(v);
    } else if (vb < 6826) {
        int idx = (vb - 576) * 1024 + tid * 4;    // 6250*1024 = exactly 6.4M floats
        float4 v = *(const float4*)(h + idx);
        ushort4 b;
        b.x = f32_to_bf16(v.x); b.y = f32_to_bf16(v.y);
        b.z = f32_to_bf16(v.z); b.w = f32_to_bf16(v.w);
        *(ushort4*)(h2 + idx) = b;
    } else if (vb < 7608) {
        int wave = tid >> 6, lane = tid & 63;
        int wid = (vb - 6826) * 4 + wave;
        int n0 = wid * 16;                        // 782*4*16 = 50048 >= 50000
        int rl = lane >> 3, seg = lane & 7;
        const float4* wp = (const float4*)(gw + rl * F + seg * 16);
        float4 w0 = wp[0], w1 = wp[1], w2 = wp[2], w3 = wp[3];
        #pragma unroll 4
        for (int i = 0; i < 16; ++i) {
            int n = n0 + i;
            if (n >= N_NODES) break;
            const float4* hp = (const float4*)(h + (size_t)n * F + seg * 16);
            float4 a0 = hp[0], a1 = hp[1], a2 = hp[2], a3 = hp[3];
            float p = a0.x * w0.x + a0.y * w0.y + a0.z * w0.z + a0.w * w0.w;
            p += a1.x * w1.x + a1.y * w1.y + a1.z * w1.z + a1.w * w1.w;
            p += a2.x * w2.x + a2.y * w2.y + a2.z * w2.z + a2.w * w2.w;
            p += a3.x * w3.x + a3.y * w3.y + a3.z * w3.z + a3.w * w3.w;
            p += __shfl_xor(p, 1);
            p += __shfl_xor(p, 2);
            p += __shfl_xor(p, 4);
            if (seg == 0) gate[(size_t)n * 8 + rl] = sigmoidf(p);
        }
    } else {
        int e = (vb - 7608) * 256 + tid;
        if (e < N_EDGES) atomicAdd(&cnt[dst[e] * 8 + rel[e]], 1);
    }
}

// ---------- v3 scan over 400000 (dst,rel) bins: s1 (local) + s2 (block sums) ----------
// s1 also zeroes cnt so it can serve as the scatter cursor; the block-offset add
// (old s3) is folded into the consumers via bsum[bin>>8].
__global__ void k_s1(int* __restrict__ cnt, int* __restrict__ excl,
                     int* __restrict__ bsum) {
    __shared__ int sh[256];
    int g = blockIdx.x * 256 + threadIdx.x;
    int v = (g < 400000) ? cnt[g] : 0;
    sh[threadIdx.x] = v;
    __syncthreads();
    #pragma unroll
    for (int off = 1; off < 256; off <<= 1) {
        int t = (threadIdx.x >= off) ? sh[threadIdx.x - off] : 0;
        __syncthreads();
        sh[threadIdx.x] += t;
        __syncthreads();
    }
    if (g < 400000) {
        excl[g] = sh[threadIdx.x] - v;   // block-local exclusive
        cnt[g] = 0;                      // reset -> scatter cursor
    }
    if (threadIdx.x == 255) bsum[blockIdx.x] = sh[255];
}

__global__ void k_s2(int* __restrict__ bsum) {   // scan NB2=1563 block sums, 1 block
    __shared__ int sh[256];
    int t = threadIdx.x;
    int v[7];
    int s = 0;
    #pragma unroll
    for (int j = 0; j < 7; ++j) {
        int idx = t * 7 + j;
        v[j] = (idx < NB2) ? bsum[idx] : 0;
        s += v[j];
    }
    sh[t] = s;
    __syncthreads();
    #pragma unroll
    for (int off = 1; off < 256; off <<= 1) {
        int tt = (t >= off) ? sh[t - off] : 0;
        __syncthreads();
        sh[t] += tt;
        __syncthreads();
    }
    int run = sh[t] - s;
    #pragma unroll
    for (int j = 0; j < 7; ++j) {
        int idx = t * 7 + j;
        if (idx < NB2) bsum[idx] = run;
        run += v[j];
    }
}

__global__ void k_scatter2(const int* __restrict__ src, const int* __restrict__ dst,
                           const int* __restrict__ rel, const float* __restrict__ norm,
                           const float* __restrict__ gate,
                           const int* __restrict__ excl, const int* __restrict__ bsum,
                           int* __restrict__ cursor, int2* __restrict__ rec) {
    int e = blockIdx.x * 256 + threadIdx.x;
    if (e >= N_EDGES) return;
    int d = dst[e], r = rel[e], s = src[e];
    int bin = d * 8 + r;
    int pos = excl[bin] + bsum[bin >> 8] + atomicAdd(&cursor[bin], 1);
    float sc = norm[e] * gate[(size_t)s * 8 + r];
    rec[pos] = make_int2(s, __float_as_int(sc));
}

// ---------- v3: per-node input-space aggregation -> A [n][8][128] bf16 (swizzled) ----------
__global__ __launch_bounds__(256) void k_aggA(const unsigned short* __restrict__ h2,
                                              const int2* __restrict__ rec,
                                              const int* __restrict__ excl,
                                              const int* __restrict__ bsum,
                                              unsigned short* __restrict__ A) {
    int wave = threadIdx.x >> 6, lane = threadIdx.x & 63;
    int n = blockIdx.x * 4 + wave;            // grid 12500 -> exactly 50000
    int ex = 0;
    if (lane < 9) {
        int bin = n * 8 + lane;
        ex = (bin < 400000) ? (excl[bin] + bsum[bin >> 8]) : N_EDGES;
    }
    int e0 = __shfl(ex, 0), e8 = __shfl(ex, 8);
    int deg = e8 - e0;
    unsigned short* Arow = A + (size_t)n * 1024;
    int swo = (((lane >> 2) ^ (n & 7)) << 2) + (lane & 3);  // swizzled uint slot in 256B seg

    if (deg <= 64) {
        int rs = 0; float rsc = 0.f;
        if (lane < deg) {
            int2 rc = rec[e0 + lane];
            rs = rc.x; rsc = __int_as_float(rc.y);
        }
        for (int r = 0; r < 8; ++r) {
            int s = __shfl(ex, r) - e0;
            int e = __shfl(ex, r + 1) - e0;
            float a0 = 0.f, a1 = 0.f;
            for (int j = s; j < e; ++j) {
                int sj = __shfl(rs, j);
                float sc = __shfl(rsc, j);
                unsigned m = *(const unsigned*)(h2 + (size_t)sj * F + lane * 2);
                a0 += sc * bf16lo(m);
                a1 += sc * bf16hi(m);
            }
            ((unsigned*)(Arow + r * 128))[swo] = packbf(a0, a1);
        }
    } else {   // safety path for high-degree nodes
        for (int r = 0; r < 8; ++r) {
            int s = __shfl(ex, r);
            int e = __shfl(ex, r + 1);
            float a0 = 0.f, a1 = 0.f;
            for (int idx = s; idx < e; ++idx) {
                int2 rc = rec[idx];                       // wave-uniform broadcast load
                float sc = __int_as_float(rc.y);
                unsigned m = *(const unsigned*)(h2 + (size_t)rc.x * F + lane * 2);
                a0 += sc * bf16lo(m);
                a1 += sc * bf16hi(m);
            }
            ((unsigned*)(Arow + r * 128))[swo] = packbf(a0, a1);
        }
    }
    // r=8 self-loop slice not materialized: k_gemmA reads h2 directly
}

// ---------- v3: out = relu([A | h2] @ W + bias), M=50000 K=9*128 N=128 ----------
// Tile 64x128, 4 waves in 2x2 (wave tile 32x64). A-fragments global->register
// (zero cross-wave A reuse -> LDS staging was pure overhead); only B staged in
// LDS (32KB, global_load_lds). Grid 782 -> ~3 blocks/CU.
__global__ __launch_bounds__(256) void k_gemmA(const unsigned short* __restrict__ A,
                                               const unsigned short* __restrict__ h2,
                                               const unsigned short* __restrict__ Wt,
                                               const float* __restrict__ bias,
                                               float* __restrict__ out) {
    __shared__ unsigned short sB[16384];   // 128 o x 128 k (swizzled granules)
    int tid = threadIdx.x;
    int nb = blockIdx.x * 64;
    int wave = tid >> 6, lane = tid & 63, lrow = lane & 15, quad = lane >> 4;
    int wr = wave >> 1, wc = wave & 1;     // 2x2 wave grid

    floatx4 acc[2][4];
    #pragma unroll
    for (int mt = 0; mt < 2; ++mt)
        #pragma unroll
        for (int nt = 0; nt < 4; ++nt) acc[mt][nt] = (floatx4){0.f, 0.f, 0.f, 0.f};

    const unsigned short* Ar0 = A + (size_t)(nb + wr * 32 + lrow) * 1024;
    const unsigned short* Ar1 = Ar0 + (size_t)16 * 1024;
    const unsigned short* Hr0 = h2 + (size_t)(nb + wr * 32 + lrow) * F;
    const unsigned short* Hr1 = Hr0 + (size_t)16 * F;
    int sk = lrow & 7;

    for (int kb = 0; kb < 9; ++kb) {
        short8 a0r[4], a1r[4];
        if (kb < 8) {
            #pragma unroll
            for (int kt = 0; kt < 4; ++kt) {
                int gphys = ((kt * 4 + quad) ^ sk) << 3;
                a0r[kt] = *(const short8*)(Ar0 + kb * 128 + gphys);
                a1r[kt] = *(const short8*)(Ar1 + kb * 128 + gphys);
            }
        } else {                               // self-loop slice straight from h2 (unswizzled)
            #pragma unroll
            for (int kt = 0; kt < 4; ++kt) {
                int goff = (kt * 4 + quad) << 3;
                a0r[kt] = *(const short8*)(Hr0 + goff);
                a1r[kt] = *(const short8*)(Hr1 + goff);
            }
        }
        __syncthreads();                       // prev compute done -> safe to overwrite sB
        #pragma unroll
        for (int it = 0; it < 8; ++it) {       // stage 32KB B slice (phys copy keeps swizzle)
            int c = it * 4 + wave;             // 1KB chunk 0..31
            gload_lds16((const char*)Wt + (kb << 15) + (c << 10) + lane * 16,
                        (char*)sB + (c << 10));
        }
        __syncthreads();                       // staging visible
        #pragma unroll
        for (int kt = 0; kt < 4; ++kt) {
            int gphys = ((kt * 4 + quad) ^ sk) << 3;
            #pragma unroll
            for (int nt = 0; nt < 4; ++nt) {
                short8 b = *(const short8*)(&sB[(wc * 64 + nt * 16 + lrow) * 128 + gphys]);
                acc[0][nt] = __builtin_amdgcn_mfma_f32_16x16x32_bf16(a0r[kt], b, acc[0][nt], 0, 0, 0);
                acc[1][nt] = __builtin_amdgcn_mfma_f32_16x16x32_bf16(a1r[kt], b, acc[1][nt], 0, 0, 0);
            }
        }
    }
    #pragma unroll
    for (int mt = 0; mt < 2; ++mt) {
        #pragma unroll
        for (int nt = 0; nt < 4; ++nt) {
            int col = wc * 64 + nt * 16 + lrow;
            float bv = bias[col];
            #pragma unroll
            for (int g = 0; g < 4; ++g) {
                int row = nb + wr * 32 + mt * 16 + quad * 4 + g;
                if (row < N_NODES)
                    out[(size_t)row * F + col] = fmaxf(acc[mt][nt][g] + bv, 0.f);
            }
        }
    }
}

// ================= legacy fallback path kernels =================
__global__ void k_prep_w(const float* __restrict__ W, const float* __restrict__ LW,
                         unsigned short* __restrict__ Wt, int swz) {
    int idx = blockIdx.x * 256 + threadIdx.x;
    if (idx >= 9 * 128 * 128) return;
    int r = idx >> 14;
    int rem = idx & 16383;
    int i = rem >> 7, o = rem & 127;
    float v = (r < 8) ? W[(r << 14) + (i << 7) + o] : LW[(i << 7) + o];
    int pos;
    if (swz) {
        int g = (i >> 3) ^ (o & 7);
        pos = (r << 14) + (o << 7) + (g << 3) + (i & 7);
    } else {
        pos = (r << 14) + (o << 7) + i;
    }
    Wt[pos] = f32_to_bf16(v);
}

__global__ void k_gate(const float* __restrict__ h, const float* __restrict__ gw,
                       float* __restrict__ gate) {
    int wave = threadIdx.x >> 6, lane = threadIdx.x & 63;
    int n = blockIdx.x * 4 + wave;
    if (n >= N_NODES) return;
    float2 hv = *(const float2*)(h + (size_t)n * F + lane * 2);
    #pragma unroll
    for (int r = 0; r < 8; ++r) {
        float2 wv = *(const float2*)(gw + r * F + lane * 2);
        float p = hv.x * wv.x + hv.y * wv.y;
        #pragma unroll
        for (int off = 32; off; off >>= 1) p += __shfl_xor(p, off);
        if (lane == 0) gate[r * N_NODES + n] = sigmoidf(p);
    }
}

#define LDH 136
#define LDW 136
__global__ __launch_bounds__(256) void k_hrel(const float* __restrict__ h,
                                              const unsigned short* __restrict__ Wt,
                                              unsigned short* __restrict__ hrel) {
    __shared__ unsigned short hA[64 * LDH];
    __shared__ unsigned short wB[128 * LDW];
    int tid = threadIdx.x;
    int nb = blockIdx.x * 64;
    #pragma unroll
    for (int it = 0; it < 8; ++it) {
        int idx = it * 1024 + tid * 4;
        int row = idx >> 7, col = idx & 127;
        int node = nb + row;
        float4 v;
        if (node < N_NODES) v = *(const float4*)(h + (size_t)node * F + col);
        else                v = make_float4(0.f, 0.f, 0.f, 0.f);
        ushort4 b;
        b.x = f32_to_bf16(v.x); b.y = f32_to_bf16(v.y);
        b.z = f32_to_bf16(v.z); b.w = f32_to_bf16(v.w);
        *(ushort4*)(&hA[row * LDH + col]) = b;
    }
    int wave = tid >> 6, lane = tid & 63;
    int lrow = lane & 15, quad = lane >> 4;
    const unsigned short* aptr = &hA[(wave * 16 + lrow) * LDH + quad * 8];
    for (int r = 0; r < NRELL; ++r) {
        __syncthreads();
        #pragma unroll
        for (int it = 0; it < 8; ++it) {
            int idx = it * 2048 + tid * 8;
            int o = idx >> 7, i = idx & 127;
            *(uint4*)(&wB[o * LDW + i]) = *(const uint4*)(Wt + (r << 14) + idx);
        }
        __syncthreads();
        floatx4 acc[8];
        #pragma unroll
        for (int nt = 0; nt < 8; ++nt) acc[nt] = (floatx4){0.f, 0.f, 0.f, 0.f};
        #pragma unroll
        for (int kt = 0; kt < 4; ++kt) {
            short8 a = *(const short8*)(aptr + kt * 32);
            #pragma unroll
            for (int nt = 0; nt < 8; ++nt) {
                short8 b = *(const short8*)(&wB[(nt * 16 + lrow) * LDW + kt * 32 + quad * 8]);
                acc[nt] = __builtin_amdgcn_mfma_f32_16x16x32_bf16(a, b, acc[nt], 0, 0, 0);
            }
        }
        unsigned short* dstp = hrel + (size_t)r * N_NODES * F;
        #pragma unroll
        for (int nt = 0; nt < 8; ++nt) {
            #pragma unroll
            for (int g = 0; g < 4; ++g) {
                int node = nb + wave * 16 + quad * 4 + g;
                if (node < N_NODES)
                    dstp[(size_t)node * F + nt * 16 + lrow] = f32_to_bf16(acc[nt][g]);
            }
        }
    }
}

__global__ void k_hist(const int* __restrict__ dst, int* __restrict__ cnt) {
    int e = blockIdx.x * 256 + threadIdx.x;
    if (e < N_EDGES) atomicAdd(&cnt[dst[e]], 1);
}

__global__ void k_scan1(const int* __restrict__ cnt, int* __restrict__ excl,
                        int* __restrict__ bsum) {
    __shared__ int sh[256];
    int g = blockIdx.x * 256 + threadIdx.x;
    int v = (g < N_NODES) ? cnt[g] : 0;
    sh[threadIdx.x] = v;
    __syncthreads();
    #pragma unroll
    for (int off = 1; off < 256; off <<= 1) {
        int t = (threadIdx.x >= off) ? sh[threadIdx.x - off] : 0;
        __syncthreads();
        sh[threadIdx.x] += t;
        __syncthreads();
    }
    if (g < N_NODES) excl[g] = sh[threadIdx.x] - v;
    if (threadIdx.x == 255) bsum[blockIdx.x] = sh[255];
}

__global__ void k_scan2(int* __restrict__ bsum) {
    __shared__ int sh[256];
    int v = (threadIdx.x < NB_SCAN) ? bsum[threadIdx.x] : 0;
    sh[threadIdx.x] = v;
    __syncthreads();
    #pragma unroll
    for (int off = 1; off < 256; off <<= 1) {
        int t = (threadIdx.x >= off) ? sh[threadIdx.x - off] : 0;
        __syncthreads();
        sh[threadIdx.x] += t;
        __syncthreads();
    }
    if (threadIdx.x < NB_SCAN) bsum[threadIdx.x] = sh[threadIdx.x] - v;
}

__global__ void k_scan3(int* __restrict__ excl, const int* __restrict__ bsum,
                        int* __restrict__ cursor) {
    int g = blockIdx.x * 256 + threadIdx.x;
    if (g < N_NODES) {
        int b = excl[g] + bsum[blockIdx.x];
        excl[g] = b;
        cursor[g] = b;
    }
}

__global__ void k_scatter(const int* __restrict__ dst, int* __restrict__ cursor,
                          int* __restrict__ sorted) {
    int e = blockIdx.x * 256 + threadIdx.x;
    if (e < N_EDGES) {
        int pos = atomicAdd(&cursor[dst[e]], 1);
        sorted[pos] = e;
    }
}

__global__ __launch_bounds__(256) void k_agg(const unsigned short* __restrict__ hrel,
                      const float* __restrict__ gate,
                      const float* __restrict__ norm,
                      const int* __restrict__ src, const int* __restrict__ rel,
                      const int* __restrict__ sorted,
                      const int* __restrict__ base, const int* __restrict__ cnt,
                      const float* __restrict__ bias,
                      float* __restrict__ out) {
    int wave = threadIdx.x >> 6, lane = threadIdx.x & 63;
    int n = blockIdx.x * 4 + wave;
    if (n >= N_NODES) return;
    int startp = base[n];
    int deg = cnt[n];
    float acc0 = 0.f, acc1 = 0.f;
    for (int c0 = 0; c0 < deg; c0 += 64) {
        int myi = c0 + lane;
        float sc = 0.f;
        int row = 0;
        if (myi < deg) {
            int e = sorted[startp + myi];
            int s = src[e], r = rel[e];
            row = r * N_NODES + s;
            sc = norm[e] * gate[row];
        }
        int lim = (deg - c0 < 64) ? (deg - c0) : 64;
        for (int i = 0; i < lim; ++i) {
            float scl = __shfl(sc, i);
            int rw = __shfl(row, i);
            unsigned m = *(const unsigned*)(hrel + (size_t)rw * F + lane * 2);
            acc0 += scl * bf16lo(m);
            acc1 += scl * bf16hi(m);
        }
    }
    const unsigned short* hrel8 = hrel + (size_t)8 * N_NODES * F;
    unsigned l8 = *(const unsigned*)(hrel8 + (size_t)n * F + lane * 2);
    float2 bv = *(const float2*)(bias + lane * 2);
    float o0 = fmaxf(acc0 + bv.x + bf16lo(l8), 0.f);
    float o1 = fmaxf(acc1 + bv.y + bf16hi(l8), 0.f);
    *(float2*)(out + (size_t)n * F + lane * 2) = make_float2(o0, o1);
}

__global__ void k_edges(const unsigned short* __restrict__ hrel,
                        const float* __restrict__ gate,
                        const float* __restrict__ norm,
                        const int* __restrict__ src, const int* __restrict__ dst,
                        const int* __restrict__ rel,
                        float* __restrict__ out) {
    int wave = threadIdx.x >> 6, lane = threadIdx.x & 63;
    int e = blockIdx.x * 4 + wave;
    if (e >= N_EDGES) return;
    int s = src[e], d = dst[e], r = rel[e];
    float scale = norm[e] * gate[r * N_NODES + s];
    unsigned int m = *(const unsigned int*)(hrel + ((size_t)r * N_NODES + s) * F + lane * 2);
    float v0 = bf16lo(m) * scale;
    float v1 = bf16hi(m) * scale;
    float* op = out + (size_t)d * F + lane * 2;
    unsafeAtomicAdd(op, v0);
    unsafeAtomicAdd(op + 1, v1);
}

__global__ void k_final(float* __restrict__ out, const float* __restrict__ bias,
                        const unsigned short* __restrict__ hrel8) {
    int idx = blockIdx.x * 256 + threadIdx.x;
    if (idx >= N_NODES * 32) return;
    int node = idx >> 5, c4 = (idx & 31) * 4;
    float4 a = *(float4*)(out + (size_t)node * F + c4);
    float4 b = *(const float4*)(bias + c4);
    ushort4 l = *(const ushort4*)(hrel8 + (size_t)node * F + c4);
    float o0 = fmaxf(a.x + b.x + bf16_to_f32(l.x), 0.f);
    float o1 = fmaxf(a.y + b.y + bf16_to_f32(l.y), 0.f);
    float o2 = fmaxf(a.z + b.z + bf16_to_f32(l.z), 0.f);
    float o3 = fmaxf(a.w + b.w + bf16_to_f32(l.w), 0.f);
    *(float4*)(out + (size_t)node * F + c4) = make_float4(o0, o1, o2, o3);
}

__global__ void k_edges_fb(const float* __restrict__ h, const float* __restrict__ W,
                           const float* __restrict__ gw, const float* __restrict__ norm,
                           const int* __restrict__ src, const int* __restrict__ dst,
                           const int* __restrict__ rel, float* __restrict__ out) {
    int wave = threadIdx.x >> 6, lane = threadIdx.x & 63;
    int e = blockIdx.x * 4 + wave;
    if (e >= N_EDGES) return;
    int s = src[e], d = dst[e], r = rel[e];
    float2 hv = *(const float2*)(h + (size_t)s * F + lane * 2);
    float2 gv = *(const float2*)(gw + r * F + lane * 2);
    float p = hv.x * gv.x + hv.y * gv.y;
    #pragma unroll
    for (int off = 32; off; off >>= 1) p += __shfl_xor(p, off);
    float scale = norm[e] * sigmoidf(p);
    const float* wr = W + ((size_t)r << 14);
    float a0 = 0.f, a1 = 0.f;
    for (int i2 = 0; i2 < 64; ++i2) {
        float x0 = __shfl(hv.x, i2), x1 = __shfl(hv.y, i2);
        a0 += x0 * wr[(2 * i2) * F + lane]      + x1 * wr[(2 * i2 + 1) * F + lane];
        a1 += x0 * wr[(2 * i2) * F + 64 + lane] + x1 * wr[(2 * i2 + 1) * F + 64 + lane];
    }
    unsafeAtomicAdd(out + (size_t)d * F + lane,      a0 * scale);
    unsafeAtomicAdd(out + (size_t)d * F + 64 + lane, a1 * scale);
}

__global__ void k_final_fb(const float* __restrict__ h, const float* __restrict__ LW,
                           const float* __restrict__ bias, float* __restrict__ out) {
    int wave = threadIdx.x >> 6, lane = threadIdx.x & 63;
    int n = blockIdx.x * 4 + wave;
    if (n >= N_NODES) return;
    float2 hv = *(const float2*)(h + (size_t)n * F + lane * 2);
    float a0 = 0.f, a1 = 0.f;
    for (int i2 = 0; i2 < 64; ++i2) {
        float x0 = __shfl(hv.x, i2), x1 = __shfl(hv.y, i2);
        a0 += x0 * LW[(2 * i2) * F + lane]      + x1 * LW[(2 * i2 + 1) * F + lane];
        a1 += x0 * LW[(2 * i2) * F + 64 + lane] + x1 * LW[(2 * i2 + 1) * F + 64 + lane];
    }
    float* op = out + (size_t)n * F;
    op[lane]      = fmaxf(op[lane]      + bias[lane]      + a0, 0.f);
    op[64 + lane] = fmaxf(op[64 + lane] + bias[64 + lane] + a1, 0.f);
}

extern "C" void kernel_launch(void* const* d_in, const int* in_sizes, int n_in,
                              void* d_out, int out_size, void* d_ws, size_t ws_size,
                              hipStream_t stream) {
    const float* h    = (const float*)d_in[0];
    const float* W    = (const float*)d_in[1];
    const float* gw   = (const float*)d_in[2];
    const float* bias = (const float*)d_in[3];
    const float* lw   = (const float*)d_in[4];
    const float* norm = (const float*)d_in[5];
    const int* src    = (const int*)d_in[6];
    const int* dst    = (const int*)d_in[7];
    const int* rel    = (const int*)d_in[8];
    float* out = (float*)d_out;

    if (ws_size >= WS_NEED3) {
        unsigned short* Wt   = (unsigned short*)((char*)d_ws + WT3_OFF);
        unsigned short* h2   = (unsigned short*)((char*)d_ws + H2_OFF);
        float*          gate = (float*)((char*)d_ws + GATE3_OFF);
        int*            cnt  = (int*)((char*)d_ws + CNT3_OFF);   // hist -> cursor
        int*            excl = (int*)((char*)d_ws + EXCL3_OFF);  // block-local scan
        int*            bsum = (int*)((char*)d_ws + BSUM3_OFF);  // exclusive block sums
        int2*           rec  = (int2*)((char*)d_ws + REC3_OFF);
        unsigned short* A    = (unsigned short*)((char*)d_ws + A3_OFF);

        hipMemsetAsync(cnt, 0, 400000 * sizeof(int), stream);
        k_prep<<<9952, 256, 0, stream>>>(h, W, gw, lw, dst, rel, Wt, h2, gate, cnt);
        k_s1<<<NB2, 256, 0, stream>>>(cnt, excl, bsum);
        k_s2<<<1, 256, 0, stream>>>(bsum);
        k_scatter2<<<2344, 256, 0, stream>>>(src, dst, rel, norm, gate, excl, bsum, cnt, rec);
        k_aggA<<<12500, 256, 0, stream>>>(h2, rec, excl, bsum, A);
        k_gemmA<<<782, 256, 0, stream>>>(A, h2, Wt, bias, out);
    } else if (ws_size >= WS_NEED2) {
        unsigned short* Wt   = (unsigned short*)d_ws;
        float*          gate = (float*)((char*)d_ws + GATE_OFF);
        unsigned short* hrel = (unsigned short*)((char*)d_ws + HREL_OFF);
        int* cnt    = (int*)((char*)d_ws + CNT_OFF);
        int* base   = (int*)((char*)d_ws + BASE_OFF);
        int* cursor = (int*)((char*)d_ws + CUR_OFF);
        int* bsum   = (int*)((char*)d_ws + BSUM_OFF);
        int* sorted = (int*)((char*)d_ws + SORT_OFF);
        hipMemsetAsync(cnt, 0, N_NODES * sizeof(int), stream);
        k_prep_w<<<576, 256, 0, stream>>>(W, lw, Wt, 0);
        k_gate<<<12500, 256, 0, stream>>>(h, gw, gate);
        k_hist<<<2344, 256, 0, stream>>>(dst, cnt);
        k_scan1<<<NB_SCAN, 256, 0, stream>>>(cnt, base, bsum);
        k_scan2<<<1, 256, 0, stream>>>(bsum);
        k_scan3<<<NB_SCAN, 256, 0, stream>>>(base, bsum, cursor);
        k_scatter<<<2344, 256, 0, stream>>>(dst, cursor, sorted);
        k_hrel<<<782, 256, 0, stream>>>(h, Wt, hrel);
        k_agg<<<12500, 256, 0, stream>>>(hrel, gate, norm, src, rel, sorted,
                                         base, cnt, bias, out);
    } else if (ws_size >= WS_NEED1) {
        unsigned short* Wt   = (unsigned short*)d_ws;
        float*          gate = (float*)((char*)d_ws + GATE_OFF);
        unsigned short* hrel = (unsigned short*)((char*)d_ws + HREL_OFF);
        hipMemsetAsync(d_out, 0, (size_t)out_size * sizeof(float), stream);
        k_prep_w<<<576, 256, 0, stream>>>(W, lw, Wt, 0);
        k_gate<<<12500, 256, 0, stream>>>(h, gw, gate);
        k_hrel<<<782, 256, 0, stream>>>(h, Wt, hrel);
        k_edges<<<150000, 256, 0, stream>>>(hrel, gate, norm, src, dst, rel, out);
        k_final<<<6250, 256, 0, stream>>>(out, bias, hrel + (size_t)8 * N_NODES * F);
    } else {
        hipMemsetAsync(d_out, 0, (size_t)out_size * sizeof(float), stream);
        k_edges_fb<<<150000, 256, 0, stream>>>(h, W, gw, norm, src, dst, rel, out);
        k_final_fb<<<12500, 256, 0, stream>>>(h, lw, bias, out);
    }
}